// Round 1
// baseline (1530.138 us; speedup 1.0000x reference)
//
#include <hip/hip_runtime.h>
#include <math.h>

#define NHEAD 8
#define NEG_SLOPE 0.2f
#define OUT_COLS 80

__device__ __forceinline__ void atomic_max_float(float* addr, float val) {
    if (val >= 0.f) atomicMax((int*)addr, __float_as_int(val));
    else            atomicMin((unsigned int*)addr, __float_as_uint(val));
}

__device__ __forceinline__ float lrelu(float x) {
    return x > 0.f ? x : NEG_SLOPE * x;
}

// One block per node: xp[n,:] = x[n,:] @ W ; fused a_s/a_d per-head dots.
template<int DIN, int HC, int C>
__global__ void proj_kernel(const float* __restrict__ xin, int xstride, int xoff,
                            const float* __restrict__ W,
                            const float* __restrict__ as_flat,
                            const float* __restrict__ ad_flat,
                            float* __restrict__ xp,
                            float* __restrict__ a_s, float* __restrict__ a_d) {
    __shared__ float xr[DIN];
    const int n = blockIdx.x;
    const int j = threadIdx.x;
    if (j < DIN) xr[j] = xin[(size_t)n * xstride + xoff + j];
    __syncthreads();
    float acc = 0.f;
#pragma unroll 8
    for (int k = 0; k < DIN; ++k) acc += xr[k] * W[k * HC + j];
    xp[(size_t)n * HC + j] = acc;
    float ps = acc * as_flat[j];
    float pd = acc * ad_flat[j];
#pragma unroll
    for (int off = C / 2; off >= 1; off >>= 1) {
        ps += __shfl_xor(ps, off, C);
        pd += __shfl_xor(pd, off, C);
    }
    if ((j & (C - 1)) == 0) {
        const int h = j / C;
        a_s[n * NHEAD + h] = ps;
        a_d[n * NHEAD + h] = pd;
    }
}

__device__ __forceinline__ void edge_src_dst(const int* __restrict__ ei, int E, int e,
                                             int& src, int& dst) {
    if (e < E) { src = ei[e]; dst = ei[E + e]; }
    else       { src = dst = e - E; }   // self-loop
}

// Pass 1: per-edge scores -> atomicMax into m[dst,h]
__global__ void edge_max_kernel(const int* __restrict__ ei, int E, int Etot,
                                const float* __restrict__ a_s,
                                const float* __restrict__ a_d,
                                float* __restrict__ m) {
    const int e = blockIdx.x * blockDim.x + threadIdx.x;
    if (e >= Etot) return;
    int src, dst; edge_src_dst(ei, E, e, src, dst);
    const float4 s0 = *(const float4*)(a_s + (size_t)src * NHEAD);
    const float4 s1 = *(const float4*)(a_s + (size_t)src * NHEAD + 4);
    const float4 d0 = *(const float4*)(a_d + (size_t)dst * NHEAD);
    const float4 d1 = *(const float4*)(a_d + (size_t)dst * NHEAD + 4);
    float sc[NHEAD] = { s0.x + d0.x, s0.y + d0.y, s0.z + d0.z, s0.w + d0.w,
                        s1.x + d1.x, s1.y + d1.y, s1.z + d1.z, s1.w + d1.w };
#pragma unroll
    for (int h = 0; h < NHEAD; ++h)
        atomic_max_float(&m[(size_t)dst * NHEAD + h], lrelu(sc[h]));
}

// Pass 2: per-edge exp(score - m) -> atomicAdd into s[dst,h]
__global__ void edge_sum_kernel(const int* __restrict__ ei, int E, int Etot,
                                const float* __restrict__ a_s,
                                const float* __restrict__ a_d,
                                const float* __restrict__ m,
                                float* __restrict__ s) {
    const int e = blockIdx.x * blockDim.x + threadIdx.x;
    if (e >= Etot) return;
    int src, dst; edge_src_dst(ei, E, e, src, dst);
    const float4 s0 = *(const float4*)(a_s + (size_t)src * NHEAD);
    const float4 s1 = *(const float4*)(a_s + (size_t)src * NHEAD + 4);
    const float4 d0 = *(const float4*)(a_d + (size_t)dst * NHEAD);
    const float4 d1 = *(const float4*)(a_d + (size_t)dst * NHEAD + 4);
    const float4 m0 = *(const float4*)(m + (size_t)dst * NHEAD);
    const float4 m1 = *(const float4*)(m + (size_t)dst * NHEAD + 4);
    float sc[NHEAD] = { s0.x + d0.x, s0.y + d0.y, s0.z + d0.z, s0.w + d0.w,
                        s1.x + d1.x, s1.y + d1.y, s1.z + d1.z, s1.w + d1.w };
    float mm[NHEAD] = { m0.x, m0.y, m0.z, m0.w, m1.x, m1.y, m1.z, m1.w };
#pragma unroll
    for (int h = 0; h < NHEAD; ++h)
        atomicAdd(&s[(size_t)dst * NHEAD + h], expf(lrelu(sc[h]) - mm[h]));
}

// Pass 3: C lanes per edge; head-summed weighted gather, one atomicAdd per (edge,c).
template<int C>
__global__ void edge_aggr_kernel(const int* __restrict__ ei, int E, int Etot,
                                 const float* __restrict__ a_s,
                                 const float* __restrict__ a_d,
                                 const float* __restrict__ m,
                                 const float* __restrict__ s,
                                 const float* __restrict__ xp,
                                 float* __restrict__ acc) {
    const int tid = blockIdx.x * blockDim.x + threadIdx.x;
    const int e = tid / C;
    const int c = tid % C;
    if (e >= Etot) return;
    int src, dst; edge_src_dst(ei, E, e, src, dst);
    float alpha = 0.f;
    if (c < NHEAD) {
        const float sc = lrelu(a_s[(size_t)src * NHEAD + c] + a_d[(size_t)dst * NHEAD + c]);
        alpha = expf(sc - m[(size_t)dst * NHEAD + c]) / s[(size_t)dst * NHEAD + c];
    }
    float sum = 0.f;
#pragma unroll
    for (int h = 0; h < NHEAD; ++h) {
        const float ah = __shfl(alpha, h, C);
        sum += ah * xp[(size_t)src * (NHEAD * C) + h * C + c];
    }
    atomicAdd(&acc[(size_t)dst * C + c], sum);
}

// Finalize: relu(acc/H + b) into the concat slice of d_out.
template<int C>
__global__ void finalize_kernel(const float* __restrict__ acc,
                                const float* __restrict__ b,
                                float* __restrict__ out, int out_off, int n_nodes) {
    const int tid = blockIdx.x * blockDim.x + threadIdx.x;
    const int n = tid / C;
    const int c = tid % C;
    if (n >= n_nodes) return;
    const float v = acc[(size_t)n * C + c] * (1.f / NHEAD) + b[c];
    out[(size_t)n * OUT_COLS + out_off + c] = fmaxf(v, 0.f);
}

static inline size_t align_up(size_t x) { return (x + 255) & ~size_t(255); }

extern "C" void kernel_launch(void* const* d_in, const int* in_sizes, int n_in,
                              void* d_out, int out_size, void* d_ws, size_t ws_size,
                              hipStream_t stream) {
    const float* x  = (const float*)d_in[0];
    const int*   ei = (const int*)d_in[1];
    const float* W1  = (const float*)d_in[2];
    const float* as1 = (const float*)d_in[3];
    const float* ad1 = (const float*)d_in[4];
    const float* b1  = (const float*)d_in[5];
    const float* W2  = (const float*)d_in[6];
    const float* as2 = (const float*)d_in[7];
    const float* ad2 = (const float*)d_in[8];
    const float* b2  = (const float*)d_in[9];
    const float* W3  = (const float*)d_in[10];
    const float* as3 = (const float*)d_in[11];
    const float* ad3 = (const float*)d_in[12];
    const float* b3  = (const float*)d_in[13];
    float* out = (float*)d_out;

    const int N = in_sizes[0] / 128;
    const int E = in_sizes[1] / 2;
    const int Etot = E + N;

    // workspace layout
    char* w = (char*)d_ws;
    float* xp  = (float*)w; w += align_up((size_t)N * 256 * 4);
    float* a_s = (float*)w; w += align_up((size_t)N * NHEAD * 4);
    float* a_d = (float*)w; w += align_up((size_t)N * NHEAD * 4);
    float* m   = (float*)w; w += align_up((size_t)N * NHEAD * 4);
    float* s   = (float*)w; w += align_up((size_t)N * NHEAD * 4);
    float* acc = (float*)w; w += align_up((size_t)N * 32 * 4);

    const int EB = 256;
    const int egrid = (Etot + EB - 1) / EB;

    // ---------------- Layer 1: din=128, C=32, HC=256 ----------------
    hipMemsetAsync(m, 0xFF, (size_t)N * NHEAD * 4, stream);
    hipMemsetAsync(s, 0,    (size_t)N * NHEAD * 4, stream);
    hipMemsetAsync(acc, 0,  (size_t)N * 32 * 4, stream);
    proj_kernel<128, 256, 32><<<N, 256, 0, stream>>>(x, 128, 0, W1, as1, ad1, xp, a_s, a_d);
    edge_max_kernel<<<egrid, EB, 0, stream>>>(ei, E, Etot, a_s, a_d, m);
    edge_sum_kernel<<<egrid, EB, 0, stream>>>(ei, E, Etot, a_s, a_d, m, s);
    {
        const long long T = (long long)Etot * 32;
        edge_aggr_kernel<32><<<(T + 255) / 256, 256, 0, stream>>>(ei, E, Etot, a_s, a_d, m, s, xp, acc);
        const long long F = (long long)N * 32;
        finalize_kernel<32><<<(F + 255) / 256, 256, 0, stream>>>(acc, b1, out, 0, N);
    }

    // ---------------- Layer 2: din=32, C=16, HC=128 (input = out[:,0:32]) ----------------
    hipMemsetAsync(m, 0xFF, (size_t)N * NHEAD * 4, stream);
    hipMemsetAsync(s, 0,    (size_t)N * NHEAD * 4, stream);
    hipMemsetAsync(acc, 0,  (size_t)N * 16 * 4, stream);
    proj_kernel<32, 128, 16><<<N, 128, 0, stream>>>(out, OUT_COLS, 0, W2, as2, ad2, xp, a_s, a_d);
    edge_max_kernel<<<egrid, EB, 0, stream>>>(ei, E, Etot, a_s, a_d, m);
    edge_sum_kernel<<<egrid, EB, 0, stream>>>(ei, E, Etot, a_s, a_d, m, s);
    {
        const long long T = (long long)Etot * 16;
        edge_aggr_kernel<16><<<(T + 255) / 256, 256, 0, stream>>>(ei, E, Etot, a_s, a_d, m, s, xp, acc);
        const long long F = (long long)N * 16;
        finalize_kernel<16><<<(F + 255) / 256, 256, 0, stream>>>(acc, b2, out, 32, N);
    }

    // ---------------- Layer 3: din=16, C=32, HC=256 (input = out[:,32:48]) ----------------
    hipMemsetAsync(m, 0xFF, (size_t)N * NHEAD * 4, stream);
    hipMemsetAsync(s, 0,    (size_t)N * NHEAD * 4, stream);
    hipMemsetAsync(acc, 0,  (size_t)N * 32 * 4, stream);
    proj_kernel<16, 256, 32><<<N, 256, 0, stream>>>(out, OUT_COLS, 32, W3, as3, ad3, xp, a_s, a_d);
    edge_max_kernel<<<egrid, EB, 0, stream>>>(ei, E, Etot, a_s, a_d, m);
    edge_sum_kernel<<<egrid, EB, 0, stream>>>(ei, E, Etot, a_s, a_d, m, s);
    {
        const long long T = (long long)Etot * 32;
        edge_aggr_kernel<32><<<(T + 255) / 256, 256, 0, stream>>>(ei, E, Etot, a_s, a_d, m, s, xp, acc);
        const long long F = (long long)N * 32;
        finalize_kernel<32><<<(F + 255) / 256, 256, 0, stream>>>(acc, b3, out, 48, N);
    }
}

// Round 2
// 992.497 us; speedup vs baseline: 1.5417x; 1.5417x over previous
//
#include <hip/hip_runtime.h>
#include <math.h>

#define NHEAD 8
#define NEG_SLOPE 0.2f
#define OUT_COLS 80

__device__ __forceinline__ float lrelu(float x) {
    return x > 0.f ? x : NEG_SLOPE * x;
}

// Register-blocked projection: thread j owns output column j for STRIP nodes.
// x-row loads are block-uniform -> scalar pipe; W chunk held in VGPRs.
// Fused per-head attention dots via __shfl_xor group reduction.
template<int DIN, int HC, int C, int STRIP>
__global__ __launch_bounds__(HC) void proj_kernel(
    const float* __restrict__ xin, int xstride, int xoff,
    const float* __restrict__ W,
    const float* __restrict__ as_flat, const float* __restrict__ ad_flat,
    float* __restrict__ xp, float* __restrict__ a_s, float* __restrict__ a_d,
    int n_nodes) {
    const int j = threadIdx.x;
    const int n0 = blockIdx.x * STRIP;
    const int nlast = n_nodes - 1;

    float acc[STRIP];
#pragma unroll
    for (int i = 0; i < STRIP; ++i) acc[i] = 0.f;

    constexpr int KC = (DIN >= 8) ? 8 : DIN;
#pragma unroll 1
    for (int k0 = 0; k0 < DIN; k0 += KC) {
        float w[KC];
#pragma unroll
        for (int kk = 0; kk < KC; ++kk) w[kk] = W[(k0 + kk) * HC + j];
#pragma unroll
        for (int i = 0; i < STRIP; ++i) {
            const int ni = n0 + i;
            const int nc = ni <= nlast ? ni : nlast;   // clamp (tail-safe)
            const float* xr = xin + (size_t)nc * xstride + xoff + k0;
#pragma unroll
            for (int kk = 0; kk < KC; ++kk) acc[i] += xr[kk] * w[kk];
        }
    }

    const float asj = as_flat[j];
    const float adj = ad_flat[j];
#pragma unroll
    for (int i = 0; i < STRIP; ++i) {
        const int ni = n0 + i;
        float ps = acc[i] * asj;
        float pd = acc[i] * adj;
#pragma unroll
        for (int off = C / 2; off >= 1; off >>= 1) {
            ps += __shfl_xor(ps, off, C);
            pd += __shfl_xor(pd, off, C);
        }
        if (ni <= nlast) {
            xp[(size_t)ni * HC + j] = acc[i];
            if ((j & (C - 1)) == 0) {
                a_s[ni * NHEAD + j / C] = ps;
                a_d[ni * NHEAD + j / C] = pd;
            }
        }
    }
}

__device__ __forceinline__ void edge_src_dst(const int* __restrict__ ei, int E, int e,
                                             int& src, int& dst) {
    if (e < E) { src = ei[e]; dst = ei[E + e]; }
    else       { src = dst = e - E; }   // self-loop
}

// Pass 1: per-edge exp(score) (no max subtraction; scores bounded) -> atomicAdd s[dst,h]
__global__ void edge_sum_kernel(const int* __restrict__ ei, int E, int Etot,
                                const float* __restrict__ a_s,
                                const float* __restrict__ a_d,
                                float* __restrict__ s) {
    const int e = blockIdx.x * blockDim.x + threadIdx.x;
    if (e >= Etot) return;
    int src, dst; edge_src_dst(ei, E, e, src, dst);
    const float4 s0 = *(const float4*)(a_s + (size_t)src * NHEAD);
    const float4 s1 = *(const float4*)(a_s + (size_t)src * NHEAD + 4);
    const float4 d0 = *(const float4*)(a_d + (size_t)dst * NHEAD);
    const float4 d1 = *(const float4*)(a_d + (size_t)dst * NHEAD + 4);
    float sc[NHEAD] = { s0.x + d0.x, s0.y + d0.y, s0.z + d0.z, s0.w + d0.w,
                        s1.x + d1.x, s1.y + d1.y, s1.z + d1.z, s1.w + d1.w };
#pragma unroll
    for (int h = 0; h < NHEAD; ++h)
        atomicAdd(&s[(size_t)dst * NHEAD + h], expf(lrelu(sc[h])));
}

// Pass 2: C lanes per edge; head-summed weighted gather, one atomicAdd per (edge,c).
template<int C>
__global__ void edge_aggr_kernel(const int* __restrict__ ei, int E, int Etot,
                                 const float* __restrict__ a_s,
                                 const float* __restrict__ a_d,
                                 const float* __restrict__ s,
                                 const float* __restrict__ xp,
                                 float* __restrict__ acc) {
    const int tid = blockIdx.x * blockDim.x + threadIdx.x;
    const int e = tid / C;
    const int c = tid % C;
    if (e >= Etot) return;
    int src, dst; edge_src_dst(ei, E, e, src, dst);
    float alpha = 0.f;
    if (c < NHEAD) {
        const float sc = lrelu(a_s[(size_t)src * NHEAD + c] + a_d[(size_t)dst * NHEAD + c]);
        alpha = expf(sc) / s[(size_t)dst * NHEAD + c];
    }
    float sum = 0.f;
#pragma unroll
    for (int h = 0; h < NHEAD; ++h) {
        const float ah = __shfl(alpha, h, C);
        sum += ah * xp[(size_t)src * (NHEAD * C) + h * C + c];
    }
    atomicAdd(&acc[(size_t)dst * C + c], sum);
}

// Finalize: relu(acc/H + b) into the concat slice of d_out.
template<int C>
__global__ void finalize_kernel(const float* __restrict__ acc,
                                const float* __restrict__ b,
                                float* __restrict__ out, int out_off, int n_nodes) {
    const int tid = blockIdx.x * blockDim.x + threadIdx.x;
    const int n = tid / C;
    const int c = tid % C;
    if (n >= n_nodes) return;
    const float v = acc[(size_t)n * C + c] * (1.f / NHEAD) + b[c];
    out[(size_t)n * OUT_COLS + out_off + c] = fmaxf(v, 0.f);
}

static inline size_t align_up(size_t x) { return (x + 255) & ~size_t(255); }

extern "C" void kernel_launch(void* const* d_in, const int* in_sizes, int n_in,
                              void* d_out, int out_size, void* d_ws, size_t ws_size,
                              hipStream_t stream) {
    const float* x  = (const float*)d_in[0];
    const int*   ei = (const int*)d_in[1];
    const float* W1  = (const float*)d_in[2];
    const float* as1 = (const float*)d_in[3];
    const float* ad1 = (const float*)d_in[4];
    const float* b1  = (const float*)d_in[5];
    const float* W2  = (const float*)d_in[6];
    const float* as2 = (const float*)d_in[7];
    const float* ad2 = (const float*)d_in[8];
    const float* b2  = (const float*)d_in[9];
    const float* W3  = (const float*)d_in[10];
    const float* as3 = (const float*)d_in[11];
    const float* ad3 = (const float*)d_in[12];
    const float* b3  = (const float*)d_in[13];
    float* out = (float*)d_out;

    const int N = in_sizes[0] / 128;
    const int E = in_sizes[1] / 2;
    const int Etot = E + N;

    // workspace layout
    char* w = (char*)d_ws;
    float* xp  = (float*)w; w += align_up((size_t)N * 256 * 4);
    float* a_s = (float*)w; w += align_up((size_t)N * NHEAD * 4);
    float* a_d = (float*)w; w += align_up((size_t)N * NHEAD * 4);
    float* s   = (float*)w; w += align_up((size_t)N * NHEAD * 4);
    float* acc = (float*)w; w += align_up((size_t)N * 32 * 4);

    const int EB = 256;
    const int egrid = (Etot + EB - 1) / EB;
    constexpr int STRIP = 16;
    const int pgrid = (N + STRIP - 1) / STRIP;

    // ---------------- Layer 1: din=128, C=32, HC=256 ----------------
    hipMemsetAsync(s, 0,   (size_t)N * NHEAD * 4, stream);
    hipMemsetAsync(acc, 0, (size_t)N * 32 * 4, stream);
    proj_kernel<128, 256, 32, STRIP><<<pgrid, 256, 0, stream>>>(x, 128, 0, W1, as1, ad1, xp, a_s, a_d, N);
    edge_sum_kernel<<<egrid, EB, 0, stream>>>(ei, E, Etot, a_s, a_d, s);
    {
        const long long T = (long long)Etot * 32;
        edge_aggr_kernel<32><<<(T + 255) / 256, 256, 0, stream>>>(ei, E, Etot, a_s, a_d, s, xp, acc);
        const long long F = (long long)N * 32;
        finalize_kernel<32><<<(F + 255) / 256, 256, 0, stream>>>(acc, b1, out, 0, N);
    }

    // ---------------- Layer 2: din=32, C=16, HC=128 (input = out[:,0:32]) ----------------
    hipMemsetAsync(s, 0,   (size_t)N * NHEAD * 4, stream);
    hipMemsetAsync(acc, 0, (size_t)N * 16 * 4, stream);
    proj_kernel<32, 128, 16, STRIP><<<pgrid, 128, 0, stream>>>(out, OUT_COLS, 0, W2, as2, ad2, xp, a_s, a_d, N);
    edge_sum_kernel<<<egrid, EB, 0, stream>>>(ei, E, Etot, a_s, a_d, s);
    {
        const long long T = (long long)Etot * 16;
        edge_aggr_kernel<16><<<(T + 255) / 256, 256, 0, stream>>>(ei, E, Etot, a_s, a_d, s, xp, acc);
        const long long F = (long long)N * 16;
        finalize_kernel<16><<<(F + 255) / 256, 256, 0, stream>>>(acc, b2, out, 32, N);
    }

    // ---------------- Layer 3: din=16, C=32, HC=256 (input = out[:,32:48]) ----------------
    hipMemsetAsync(s, 0,   (size_t)N * NHEAD * 4, stream);
    hipMemsetAsync(acc, 0, (size_t)N * 32 * 4, stream);
    proj_kernel<16, 256, 32, STRIP><<<pgrid, 256, 0, stream>>>(out, OUT_COLS, 32, W3, as3, ad3, xp, a_s, a_d, N);
    edge_sum_kernel<<<egrid, EB, 0, stream>>>(ei, E, Etot, a_s, a_d, s);
    {
        const long long T = (long long)Etot * 32;
        edge_aggr_kernel<32><<<(T + 255) / 256, 256, 0, stream>>>(ei, E, Etot, a_s, a_d, s, xp, acc);
        const long long F = (long long)N * 32;
        finalize_kernel<32><<<(F + 255) / 256, 256, 0, stream>>>(acc, b3, out, 48, N);
    }
}

// Round 3
// 577.369 us; speedup vs baseline: 2.6502x; 1.7190x over previous
//
#include <hip/hip_runtime.h>
#include <math.h>

#define NHEAD 8
#define NEG_SLOPE 0.2f
#define OUT_COLS 80

__device__ __forceinline__ float lrelu(float x) {
    return x > 0.f ? x : NEG_SLOPE * x;
}

// ---------------- projection: thread j owns column j for STRIP nodes ----------------
// W chunk double-buffered in VGPRs (prefetch next chunk during FMAs); x via float4.
template<int DIN, int HC, int C, int STRIP, int KC>
__global__ __launch_bounds__(HC) void proj_kernel(
    const float* __restrict__ xin, int xstride, int xoff,
    const float* __restrict__ W,
    const float* __restrict__ as_flat, const float* __restrict__ ad_flat,
    float* __restrict__ xp, float* __restrict__ a_s, float* __restrict__ a_d,
    int n_nodes) {
    const int j = threadIdx.x;
    const int n0 = blockIdx.x * STRIP;
    const int nlast = n_nodes - 1;

    float acc[STRIP];
#pragma unroll
    for (int i = 0; i < STRIP; ++i) acc[i] = 0.f;

    float wc[KC], wn[KC];
#pragma unroll
    for (int kk = 0; kk < KC; ++kk) wc[kk] = W[kk * HC + j];

#pragma unroll 1
    for (int k0 = 0; k0 < DIN; k0 += KC) {
        const bool more = (k0 + KC) < DIN;
        if (more) {
#pragma unroll
            for (int kk = 0; kk < KC; ++kk) wn[kk] = W[(k0 + KC + kk) * HC + j];
        }
#pragma unroll
        for (int i = 0; i < STRIP; ++i) {
            const int ni = n0 + i;
            const int nc = ni <= nlast ? ni : nlast;   // clamp (tail-safe)
            const float* xr = xin + (size_t)nc * xstride + xoff + k0;
#pragma unroll
            for (int kk = 0; kk < KC; kk += 4) {
                const float4 xv = *(const float4*)(xr + kk);
                acc[i] += xv.x * wc[kk] + xv.y * wc[kk + 1] + xv.z * wc[kk + 2] + xv.w * wc[kk + 3];
            }
        }
        if (more) {
#pragma unroll
            for (int kk = 0; kk < KC; ++kk) wc[kk] = wn[kk];
        }
    }

    const float asj = as_flat[j];
    const float adj = ad_flat[j];
#pragma unroll
    for (int i = 0; i < STRIP; ++i) {
        const int ni = n0 + i;
        float ps = acc[i] * asj;
        float pd = acc[i] * adj;
#pragma unroll
        for (int off = C / 2; off >= 1; off >>= 1) {
            ps += __shfl_xor(ps, off, C);
            pd += __shfl_xor(pd, off, C);
        }
        if (ni <= nlast) {
            xp[(size_t)ni * HC + j] = acc[i];
            if ((j & (C - 1)) == 0) {
                a_s[ni * NHEAD + j / C] = ps;
                a_d[ni * NHEAD + j / C] = pd;
            }
        }
    }
}

// ---------------- CSR build ----------------
__global__ void hist_kernel(const int* __restrict__ ei, int E, int* __restrict__ deg) {
    const int e = blockIdx.x * blockDim.x + threadIdx.x;
    if (e < E) atomicAdd(&deg[ei[E + e]], 1);
}

// single-block exclusive scan of deg -> rowptr & cursor; rowptr[N]=E.
__global__ __launch_bounds__(1024) void scan_kernel(const int* __restrict__ deg,
                                                    int* __restrict__ rowptr,
                                                    int* __restrict__ cursor, int N) {
    __shared__ int part[1024];
    const int t = threadIdx.x;
    const int CH = (N + 1023) / 1024;
    const int lo = min(t * CH, N), hi = min(lo + CH, N);
    int sum = 0;
    for (int i = lo; i < hi; ++i) sum += deg[i];
    part[t] = sum;
    __syncthreads();
    for (int off = 1; off < 1024; off <<= 1) {
        const int u = (t >= off) ? part[t - off] : 0;
        __syncthreads();
        part[t] += u;
        __syncthreads();
    }
    int run = part[t] - sum;   // exclusive base
    for (int i = lo; i < hi; ++i) {
        rowptr[i] = run;
        cursor[i] = run;
        run += deg[i];
    }
    if (t == 1023) rowptr[N] = part[1023];
}

__global__ void scatter_kernel(const int* __restrict__ ei, int E,
                               int* __restrict__ cursor, int* __restrict__ csr_src) {
    const int e = blockIdx.x * blockDim.x + threadIdx.x;
    if (e < E) {
        const int pos = atomicAdd(&cursor[ei[E + e]], 1);
        csr_src[pos] = ei[e];
    }
}

// ---------------- pass A: per-dst softmax denominators (no atomics) ----------------
// one wave per dst; lane = i*8+h (i = edge slot, h = head)
__global__ void attn_kernel(const int* __restrict__ rowptr, const int* __restrict__ csr_src,
                            const float* __restrict__ a_s, const float* __restrict__ a_d,
                            float* __restrict__ s, int N) {
    const int wave = (blockIdx.x * blockDim.x + threadIdx.x) >> 6;
    if (wave >= N) return;
    const int lane = threadIdx.x & 63;
    const int i = lane >> 3, h = lane & 7;
    const int n = wave;
    const int row0 = rowptr[n];
    const int deg = rowptr[n + 1] - row0;
    const float adh = a_d[n * NHEAD + h];
    const float ash = a_s[n * NHEAD + h];
    float sacc = (i == 0) ? expf(lrelu(ash + adh)) : 0.f;   // self-loop
    for (int base = 0; base < deg; base += 8) {
        const int idx = base + i;
        if (idx < deg) {
            const int src = csr_src[row0 + idx];
            sacc += expf(lrelu(a_s[src * NHEAD + h] + adh));
        }
    }
    sacc += __shfl_xor(sacc, 8, 64);
    sacc += __shfl_xor(sacc, 16, 64);
    sacc += __shfl_xor(sacc, 32, 64);
    if (lane < NHEAD) s[n * NHEAD + lane] = sacc;
}

// ---------------- pass B: per-dst aggregation (no atomics), fused mean+bias+relu ----------------
// one wave per dst; lane = hh*C + c; head(hp) = hp*G + hh  (G = 64/C)
template<int C>
__global__ void aggr_kernel(const int* __restrict__ rowptr, const int* __restrict__ csr_src,
                            const float* __restrict__ a_s, const float* __restrict__ a_d,
                            const float* __restrict__ s, const float* __restrict__ xp,
                            const float* __restrict__ bias,
                            float* __restrict__ out, int out_off, int N) {
    constexpr int HC = NHEAD * C;
    constexpr int G = 64 / C;
    constexpr int HP = NHEAD / G;
    const int wave = (blockIdx.x * blockDim.x + threadIdx.x) >> 6;
    if (wave >= N) return;
    const int lane = threadIdx.x & 63;
    const int c = lane & (C - 1);
    const int hh = lane / C;
    const int n = wave;
    const int row0 = rowptr[n];
    const int deg = rowptr[n + 1] - row0;

    float sinv[HP], adh[HP];
#pragma unroll
    for (int hp = 0; hp < HP; ++hp) {
        const int h = hp * G + hh;
        sinv[hp] = 1.f / s[n * NHEAD + h];
        adh[hp] = a_d[n * NHEAD + h];
    }

    float acc = 0.f;
    // self-loop (src = n)
#pragma unroll
    for (int hp = 0; hp < HP; ++hp) {
        const int h = hp * G + hh;
        const float alpha = expf(lrelu(a_s[n * NHEAD + h] + adh[hp])) * sinv[hp];
        acc += alpha * xp[(size_t)n * HC + h * C + c];
    }
    for (int e2 = 0; e2 < deg; ++e2) {
        const int src = csr_src[row0 + e2];
#pragma unroll
        for (int hp = 0; hp < HP; ++hp) {
            const int h = hp * G + hh;
            const float alpha = expf(lrelu(a_s[src * NHEAD + h] + adh[hp])) * sinv[hp];
            acc += alpha * xp[(size_t)src * HC + h * C + c];
        }
    }
#pragma unroll
    for (int off = 32; off >= C; off >>= 1) acc += __shfl_xor(acc, off, 64);
    if (lane < C) {
        const float v = acc * (1.f / NHEAD) + bias[lane];
        out[(size_t)n * OUT_COLS + out_off + lane] = fmaxf(v, 0.f);
    }
}

static inline size_t align_up(size_t x) { return (x + 255) & ~size_t(255); }

extern "C" void kernel_launch(void* const* d_in, const int* in_sizes, int n_in,
                              void* d_out, int out_size, void* d_ws, size_t ws_size,
                              hipStream_t stream) {
    const float* x  = (const float*)d_in[0];
    const int*   ei = (const int*)d_in[1];
    const float* W1  = (const float*)d_in[2];
    const float* as1 = (const float*)d_in[3];
    const float* ad1 = (const float*)d_in[4];
    const float* b1  = (const float*)d_in[5];
    const float* W2  = (const float*)d_in[6];
    const float* as2 = (const float*)d_in[7];
    const float* ad2 = (const float*)d_in[8];
    const float* b2  = (const float*)d_in[9];
    const float* W3  = (const float*)d_in[10];
    const float* as3 = (const float*)d_in[11];
    const float* ad3 = (const float*)d_in[12];
    const float* b3  = (const float*)d_in[13];
    float* out = (float*)d_out;

    const int N = in_sizes[0] / 128;
    const int E = in_sizes[1] / 2;

    // workspace layout (~58 MB)
    char* w = (char*)d_ws;
    float* xp     = (float*)w; w += align_up((size_t)N * 256 * 4);
    float* a_s    = (float*)w; w += align_up((size_t)N * NHEAD * 4);
    float* a_d    = (float*)w; w += align_up((size_t)N * NHEAD * 4);
    float* s      = (float*)w; w += align_up((size_t)N * NHEAD * 4);
    int*   deg    = (int*)w;   w += align_up((size_t)N * 4);
    int*   rowptr = (int*)w;   w += align_up((size_t)(N + 1) * 4);
    int*   cursor = (int*)w;   w += align_up((size_t)N * 4);
    int*   csrsrc = (int*)w;   w += align_up((size_t)E * 4);

    const int EB = 256;
    const int eg = (E + EB - 1) / EB;
    constexpr int STRIP = 16;
    const int pgrid = (N + STRIP - 1) / STRIP;
    const int ngrid = (N + 3) / 4;     // 4 waves (dsts) per 256-thread block

    // ---- CSR build (once, reused by all 3 layers) ----
    hipMemsetAsync(deg, 0, (size_t)N * 4, stream);
    hist_kernel<<<eg, EB, 0, stream>>>(ei, E, deg);
    scan_kernel<<<1, 1024, 0, stream>>>(deg, rowptr, cursor, N);
    scatter_kernel<<<eg, EB, 0, stream>>>(ei, E, cursor, csrsrc);

    // ---------------- Layer 1: din=128, C=32, HC=256 ----------------
    proj_kernel<128, 256, 32, STRIP, 16><<<pgrid, 256, 0, stream>>>(x, 128, 0, W1, as1, ad1, xp, a_s, a_d, N);
    attn_kernel<<<ngrid, 256, 0, stream>>>(rowptr, csrsrc, a_s, a_d, s, N);
    aggr_kernel<32><<<ngrid, 256, 0, stream>>>(rowptr, csrsrc, a_s, a_d, s, xp, b1, out, 0, N);

    // ---------------- Layer 2: din=32, C=16, HC=128 (input = out[:,0:32]) ----------------
    proj_kernel<32, 128, 16, STRIP, 16><<<pgrid, 128, 0, stream>>>(out, OUT_COLS, 0, W2, as2, ad2, xp, a_s, a_d, N);
    attn_kernel<<<ngrid, 256, 0, stream>>>(rowptr, csrsrc, a_s, a_d, s, N);
    aggr_kernel<16><<<ngrid, 256, 0, stream>>>(rowptr, csrsrc, a_s, a_d, s, xp, b2, out, 32, N);

    // ---------------- Layer 3: din=16, C=32, HC=256 (input = out[:,32:48]) ----------------
    proj_kernel<16, 256, 32, STRIP, 16><<<pgrid, 256, 0, stream>>>(out, OUT_COLS, 32, W3, as3, ad3, xp, a_s, a_d, N);
    attn_kernel<<<ngrid, 256, 0, stream>>>(rowptr, csrsrc, a_s, a_d, s, N);
    aggr_kernel<32><<<ngrid, 256, 0, stream>>>(rowptr, csrsrc, a_s, a_d, s, xp, b3, out, 48, N);
}

// Round 4
// 447.955 us; speedup vs baseline: 3.4158x; 1.2889x over previous
//
#include <hip/hip_runtime.h>
#include <math.h>

#define NHEAD 8
#define NEG_SLOPE 0.2f
#define OUT_COLS 80

__device__ __forceinline__ float lrelu(float x) {
    return x > 0.f ? x : NEG_SLOPE * x;
}

// ---------------- projection (outer-product register tile) ----------------
// Block = 4 waves (256 thr). Wave: 64 nodes (lane = node) x 32 cols (j0).
// grid.x = HC/128 col-groups, grid.y = node tiles (adjacent blocks share x rows -> L1/L2 hits).
// W loads are wave-uniform (readfirstlane'd j0) -> scalar-cache path; x loads per-lane float4.
template<int DIN, int HC, int C>
__global__ __launch_bounds__(256) void proj_kernel(
    const float* __restrict__ xin, int xstride, int xoff,
    const float* __restrict__ W,
    const float* __restrict__ as_flat, const float* __restrict__ ad_flat,
    float* __restrict__ xp, float* __restrict__ a_s, float* __restrict__ a_d,
    int n_nodes) {
    const int lane = threadIdx.x & 63;
    const int wv = threadIdx.x >> 6;                    // wave id 0..3
    const int j0 = blockIdx.x * 128 + wv * 32;          // col chunk
    const int j0u = __builtin_amdgcn_readfirstlane(j0);
    const int n = blockIdx.y * 64 + lane;
    const int nc = n < n_nodes ? n : n_nodes - 1;       // clamp (tail-safe)

    float acc[32];
#pragma unroll
    for (int q = 0; q < 32; ++q) acc[q] = 0.f;

    const float* __restrict__ xrow = xin + (size_t)nc * xstride + xoff;

#pragma unroll 2
    for (int k4 = 0; k4 < DIN / 4; ++k4) {
        const float4 xv = *(const float4*)(xrow + k4 * 4);
#pragma unroll
        for (int kk = 0; kk < 4; ++kk) {
            const float xk = kk == 0 ? xv.x : kk == 1 ? xv.y : kk == 2 ? xv.z : xv.w;
            const float4* __restrict__ W4 =
                (const float4*)(W + (size_t)(k4 * 4 + kk) * HC + j0u);
#pragma unroll
            for (int q = 0; q < 8; ++q) {
                const float4 wv4 = W4[q];
                acc[q * 4 + 0] += xk * wv4.x;
                acc[q * 4 + 1] += xk * wv4.y;
                acc[q * 4 + 2] += xk * wv4.z;
                acc[q * 4 + 3] += xk * wv4.w;
            }
        }
    }

    // attention dots: C=32 -> this chunk is exactly head (j0/32);
    // C=16 -> two heads (j0/16, j0/16+1). Lane-local, no shuffles.
    float ps[2] = {0.f, 0.f}, pd[2] = {0.f, 0.f};
#pragma unroll
    for (int q = 0; q < 32; ++q) {
        const int g = (C == 16 && q >= 16) ? 1 : 0;
        ps[g] += acc[q] * as_flat[j0u + q];
        pd[g] += acc[q] * ad_flat[j0u + q];
    }

    if (n < n_nodes) {
#pragma unroll
        for (int q = 0; q < 8; ++q) {
            *(float4*)(xp + (size_t)n * HC + j0 + q * 4) =
                make_float4(acc[q * 4], acc[q * 4 + 1], acc[q * 4 + 2], acc[q * 4 + 3]);
        }
        if (C == 32) {
            const int h = j0 / 32;
            a_s[(size_t)n * NHEAD + h] = ps[0];
            a_d[(size_t)n * NHEAD + h] = pd[0];
        } else {
            const int h = j0 / 16;
            a_s[(size_t)n * NHEAD + h] = ps[0];
            a_s[(size_t)n * NHEAD + h + 1] = ps[1];
            a_d[(size_t)n * NHEAD + h] = pd[0];
            a_d[(size_t)n * NHEAD + h + 1] = pd[1];
        }
    }
}

// ---------------- CSR build ----------------
__global__ void hist_kernel(const int* __restrict__ ei, int E, int* __restrict__ deg) {
    const int e = blockIdx.x * blockDim.x + threadIdx.x;
    if (e < E) atomicAdd(&deg[ei[E + e]], 1);
}

__global__ __launch_bounds__(1024) void scan_kernel(const int* __restrict__ deg,
                                                    int* __restrict__ rowptr,
                                                    int* __restrict__ cursor, int N) {
    __shared__ int part[1024];
    const int t = threadIdx.x;
    const int CH = (N + 1023) / 1024;
    const int lo = min(t * CH, N), hi = min(lo + CH, N);
    int sum = 0;
    for (int i = lo; i < hi; ++i) sum += deg[i];
    part[t] = sum;
    __syncthreads();
    for (int off = 1; off < 1024; off <<= 1) {
        const int u = (t >= off) ? part[t - off] : 0;
        __syncthreads();
        part[t] += u;
        __syncthreads();
    }
    int run = part[t] - sum;   // exclusive base
    for (int i = lo; i < hi; ++i) {
        rowptr[i] = run;
        cursor[i] = run;
        run += deg[i];
    }
    if (t == 1023) rowptr[N] = part[1023];
}

__global__ void scatter_kernel(const int* __restrict__ ei, int E,
                               int* __restrict__ cursor, int* __restrict__ csr_src) {
    const int e = blockIdx.x * blockDim.x + threadIdx.x;
    if (e < E) {
        const int pos = atomicAdd(&cursor[ei[E + e]], 1);
        csr_src[pos] = ei[e];
    }
}

// ---------------- fused softmax+aggregation: one wave per dst ----------------
// Normalization is linear: accumulate unnormalized sum(ex*xp) per head and sum(ex),
// divide at the end. Phase A: lane=(slot i, head h) computes ex for 8 edges.
// Phase B: redistribute ex/src via shfl; lane=(hh,c) gathers xp and FMAs.
template<int C>
__global__ __launch_bounds__(256) void aggr_kernel(
    const int* __restrict__ rowptr, const int* __restrict__ csr_src,
    const float* __restrict__ a_s, const float* __restrict__ a_d,
    const float* __restrict__ xp, const float* __restrict__ bias,
    float* __restrict__ out, int out_off, int N) {
    constexpr int HC = NHEAD * C;
    constexpr int G = 64 / C;       // lanes per col position (2 or 4)
    constexpr int HP = NHEAD / G;   // heads per lane (4 or 2)
    const int wave = (blockIdx.x * blockDim.x + threadIdx.x) >> 6;
    if (wave >= N) return;
    const int lane = threadIdx.x & 63;
    const int n = wave;
    const int iA = lane >> 3, hA = lane & 7;    // phase-A role
    const int c = lane & (C - 1);               // phase-B role
    const int hh = lane / C;
    const int row0 = rowptr[n];
    const int deg = rowptr[n + 1] - row0;

    const float adhA = a_d[(size_t)n * NHEAD + hA];
    float adhB[HP];
#pragma unroll
    for (int hp = 0; hp < HP; ++hp) adhB[hp] = a_d[(size_t)n * NHEAD + hp * G + hh];

    float sacc = 0.f;
    float acc[HP];
#pragma unroll
    for (int hp = 0; hp < HP; ++hp) acc[hp] = 0.f;

    for (int base = 0; base < deg; base += 8) {
        const int idx = base + iA;
        int src = 0;
        float ex = 0.f;
        if (idx < deg) {
            src = csr_src[row0 + idx];
            ex = expf(lrelu(a_s[(size_t)src * NHEAD + hA] + adhA));
        }
        sacc += ex;
        const int cnt = min(deg - base, 8);
        for (int e2 = 0; e2 < cnt; ++e2) {
            const int s2 = __shfl(src, e2 * 8, 64);
#pragma unroll
            for (int hp = 0; hp < HP; ++hp) {
                const float exh = __shfl(ex, e2 * 8 + hp * G + hh, 64);
                acc[hp] += exh * xp[(size_t)s2 * HC + (hp * G + hh) * C + c];
            }
        }
    }
    // total edge-ex per head: combine slot lanes; lane L ends with s_edges(h = L&7)
    sacc += __shfl_xor(sacc, 8, 64);
    sacc += __shfl_xor(sacc, 16, 64);
    sacc += __shfl_xor(sacc, 32, 64);

    // self-loop + per-head normalize
    float total = 0.f;
#pragma unroll
    for (int hp = 0; hp < HP; ++hp) {
        const int h = hp * G + hh;
        const float exs = expf(lrelu(a_s[(size_t)n * NHEAD + h] + adhB[hp]));
        const float s_h = __shfl(sacc, h, 64) + exs;
        const float acch = acc[hp] + exs * xp[(size_t)n * HC + h * C + c];
        total += acch / s_h;
    }
#pragma unroll
    for (int off = 32; off >= C; off >>= 1) total += __shfl_xor(total, off, 64);
    if (lane < C) {
        out[(size_t)n * OUT_COLS + out_off + lane] =
            fmaxf(total * (1.f / NHEAD) + bias[lane], 0.f);
    }
}

static inline size_t align_up(size_t x) { return (x + 255) & ~size_t(255); }

extern "C" void kernel_launch(void* const* d_in, const int* in_sizes, int n_in,
                              void* d_out, int out_size, void* d_ws, size_t ws_size,
                              hipStream_t stream) {
    const float* x  = (const float*)d_in[0];
    const int*   ei = (const int*)d_in[1];
    const float* W1  = (const float*)d_in[2];
    const float* as1 = (const float*)d_in[3];
    const float* ad1 = (const float*)d_in[4];
    const float* b1  = (const float*)d_in[5];
    const float* W2  = (const float*)d_in[6];
    const float* as2 = (const float*)d_in[7];
    const float* ad2 = (const float*)d_in[8];
    const float* b2  = (const float*)d_in[9];
    const float* W3  = (const float*)d_in[10];
    const float* as3 = (const float*)d_in[11];
    const float* ad3 = (const float*)d_in[12];
    const float* b3  = (const float*)d_in[13];
    float* out = (float*)d_out;

    const int N = in_sizes[0] / 128;
    const int E = in_sizes[1] / 2;

    // workspace layout (~58 MB)
    char* w = (char*)d_ws;
    float* xp     = (float*)w; w += align_up((size_t)N * 256 * 4);
    float* a_s    = (float*)w; w += align_up((size_t)N * NHEAD * 4);
    float* a_d    = (float*)w; w += align_up((size_t)N * NHEAD * 4);
    int*   deg    = (int*)w;   w += align_up((size_t)N * 4);
    int*   rowptr = (int*)w;   w += align_up((size_t)(N + 1) * 4);
    int*   cursor = (int*)w;   w += align_up((size_t)N * 4);
    int*   csrsrc = (int*)w;   w += align_up((size_t)E * 4);

    const int EB = 256;
    const int eg = (E + EB - 1) / EB;
    const int ntiles = (N + 63) / 64;
    const int ngrid = (N + 3) / 4;     // 4 dst-waves per 256-thread block

    // ---- CSR build (once, reused by all 3 layers) ----
    hipMemsetAsync(deg, 0, (size_t)N * 4, stream);
    hist_kernel<<<eg, EB, 0, stream>>>(ei, E, deg);
    scan_kernel<<<1, 1024, 0, stream>>>(deg, rowptr, cursor, N);
    scatter_kernel<<<eg, EB, 0, stream>>>(ei, E, cursor, csrsrc);

    // ---------------- Layer 1: din=128, C=32, HC=256 ----------------
    proj_kernel<128, 256, 32><<<dim3(2, ntiles), 256, 0, stream>>>(
        x, 128, 0, W1, as1, ad1, xp, a_s, a_d, N);
    aggr_kernel<32><<<ngrid, 256, 0, stream>>>(rowptr, csrsrc, a_s, a_d, xp, b1, out, 0, N);

    // ---------------- Layer 2: din=32, C=16, HC=128 (input = out[:,0:32]) ----------------
    proj_kernel<32, 128, 16><<<dim3(1, ntiles), 256, 0, stream>>>(
        out, OUT_COLS, 0, W2, as2, ad2, xp, a_s, a_d, N);
    aggr_kernel<16><<<ngrid, 256, 0, stream>>>(rowptr, csrsrc, a_s, a_d, xp, b2, out, 32, N);

    // ---------------- Layer 3: din=16, C=32, HC=256 (input = out[:,32:48]) ----------------
    proj_kernel<16, 256, 32><<<dim3(2, ntiles), 256, 0, stream>>>(
        out, OUT_COLS, 32, W3, as3, ad3, xp, a_s, a_d, N);
    aggr_kernel<32><<<ngrid, 256, 0, stream>>>(rowptr, csrsrc, a_s, a_d, xp, b3, out, 48, N);
}

// Round 5
// 346.235 us; speedup vs baseline: 4.4194x; 1.2938x over previous
//
#include <hip/hip_runtime.h>
#include <math.h>

#define NHEAD 8
#define NEG_SLOPE 0.2f
#define OUT_COLS 80

__device__ __forceinline__ float lrelu(float x) {
    return x > 0.f ? x : NEG_SLOPE * x;
}

// ---------------- projection (outer-product register tile) ----------------
// Block = 4 waves (256 thr). Wave: 64 nodes (lane = node) x 32 cols (j0).
template<int DIN, int HC, int C>
__global__ __launch_bounds__(256) void proj_kernel(
    const float* __restrict__ xin, int xstride, int xoff,
    const float* __restrict__ W,
    const float* __restrict__ as_flat, const float* __restrict__ ad_flat,
    float* __restrict__ xp, float* __restrict__ a_s, float* __restrict__ a_d,
    int n_nodes) {
    const int lane = threadIdx.x & 63;
    const int wv = threadIdx.x >> 6;                    // wave id 0..3
    const int j0 = blockIdx.x * 128 + wv * 32;          // col chunk
    const int j0u = __builtin_amdgcn_readfirstlane(j0);
    const int n = blockIdx.y * 64 + lane;
    const int nc = n < n_nodes ? n : n_nodes - 1;       // clamp (tail-safe)

    float acc[32];
#pragma unroll
    for (int q = 0; q < 32; ++q) acc[q] = 0.f;

    const float* __restrict__ xrow = xin + (size_t)nc * xstride + xoff;

#pragma unroll 2
    for (int k4 = 0; k4 < DIN / 4; ++k4) {
        const float4 xv = *(const float4*)(xrow + k4 * 4);
#pragma unroll
        for (int kk = 0; kk < 4; ++kk) {
            const float xk = kk == 0 ? xv.x : kk == 1 ? xv.y : kk == 2 ? xv.z : xv.w;
            const float4* __restrict__ W4 =
                (const float4*)(W + (size_t)(k4 * 4 + kk) * HC + j0u);
#pragma unroll
            for (int q = 0; q < 8; ++q) {
                const float4 wv4 = W4[q];
                acc[q * 4 + 0] += xk * wv4.x;
                acc[q * 4 + 1] += xk * wv4.y;
                acc[q * 4 + 2] += xk * wv4.z;
                acc[q * 4 + 3] += xk * wv4.w;
            }
        }
    }

    float ps[2] = {0.f, 0.f}, pd[2] = {0.f, 0.f};
#pragma unroll
    for (int q = 0; q < 32; ++q) {
        const int g = (C == 16 && q >= 16) ? 1 : 0;
        ps[g] += acc[q] * as_flat[j0u + q];
        pd[g] += acc[q] * ad_flat[j0u + q];
    }

    if (n < n_nodes) {
#pragma unroll
        for (int q = 0; q < 8; ++q) {
            *(float4*)(xp + (size_t)n * HC + j0 + q * 4) =
                make_float4(acc[q * 4], acc[q * 4 + 1], acc[q * 4 + 2], acc[q * 4 + 3]);
        }
        if (C == 32) {
            const int h = j0 / 32;
            a_s[(size_t)n * NHEAD + h] = ps[0];
            a_d[(size_t)n * NHEAD + h] = pd[0];
        } else {
            const int h = j0 / 16;
            a_s[(size_t)n * NHEAD + h] = ps[0];
            a_s[(size_t)n * NHEAD + h + 1] = ps[1];
            a_d[(size_t)n * NHEAD + h] = pd[0];
            a_d[(size_t)n * NHEAD + h + 1] = pd[1];
        }
    }
}

// ---------------- CSR build ----------------
__global__ void hist_kernel(const int* __restrict__ ei, int E, int* __restrict__ deg) {
    const int e = blockIdx.x * blockDim.x + threadIdx.x;
    if (e < E) atomicAdd(&deg[ei[E + e]], 1);
}

// Multi-block scan, stage 1: per-1024-chunk sums.
__global__ __launch_bounds__(256) void blocksum_kernel(const int* __restrict__ deg, int N,
                                                       int* __restrict__ bsum) {
    __shared__ int red[256];
    const int t = threadIdx.x;
    const int base = blockIdx.x * 1024 + t * 4;
    int s = 0;
    if (base + 3 < N) {
        const int4 v = *(const int4*)(deg + base);
        s = v.x + v.y + v.z + v.w;
    } else {
#pragma unroll
        for (int i = 0; i < 4; ++i) if (base + i < N) s += deg[base + i];
    }
    red[t] = s;
    __syncthreads();
    for (int off = 128; off > 0; off >>= 1) {
        if (t < off) red[t] += red[t + off];
        __syncthreads();
    }
    if (t == 0) bsum[blockIdx.x] = red[0];
}

// Stage 2: one wave, in-place exclusive scan of block sums (NB up to a few thousand).
__global__ __launch_bounds__(64) void bscan_kernel(int* __restrict__ bsum, int NB) {
    const int lane = threadIdx.x;
    int run = 0;
    for (int base = 0; base < NB; base += 64) {
        const int i = base + lane;
        const int v = (i < NB) ? bsum[i] : 0;
        int inc = v;
#pragma unroll
        for (int off = 1; off < 64; off <<= 1) {
            const int u = __shfl_up(inc, off, 64);
            if (lane >= off) inc += u;
        }
        if (i < NB) bsum[i] = run + inc - v;   // exclusive
        run += __shfl(inc, 63, 64);
    }
}

// Stage 3: per-chunk exclusive scan + block base -> rowptr & cursor.
__global__ __launch_bounds__(256) void rowptr_kernel(const int* __restrict__ deg,
                                                     const int* __restrict__ bsum,
                                                     int N, int E,
                                                     int* __restrict__ rowptr,
                                                     int* __restrict__ cursor) {
    __shared__ int tsum[256];
    const int t = threadIdx.x;
    const int base = blockIdx.x * 1024 + t * 4;
    int v[4];
    int s = 0;
#pragma unroll
    for (int i = 0; i < 4; ++i) {
        v[i] = (base + i < N) ? deg[base + i] : 0;
        s += v[i];
    }
    tsum[t] = s;
    __syncthreads();
    for (int off = 1; off < 256; off <<= 1) {
        const int u = (t >= off) ? tsum[t - off] : 0;
        __syncthreads();
        tsum[t] += u;
        __syncthreads();
    }
    int run = bsum[blockIdx.x] + tsum[t] - s;
#pragma unroll
    for (int i = 0; i < 4; ++i) {
        if (base + i < N) {
            rowptr[base + i] = run;
            cursor[base + i] = run;
            run += v[i];
        }
    }
    if (blockIdx.x == 0 && t == 0) rowptr[N] = E;
}

__global__ void scatter_kernel(const int* __restrict__ ei, int E,
                               int* __restrict__ cursor, int* __restrict__ csr_src) {
    const int e = blockIdx.x * blockDim.x + threadIdx.x;
    if (e < E) {
        const int pos = atomicAdd(&cursor[ei[E + e]], 1);
        csr_src[pos] = ei[e];
    }
}

// ---------------- fused softmax+aggregation: one wave per dst ----------------
template<int C>
__global__ __launch_bounds__(256) void aggr_kernel(
    const int* __restrict__ rowptr, const int* __restrict__ csr_src,
    const float* __restrict__ a_s, const float* __restrict__ a_d,
    const float* __restrict__ xp, const float* __restrict__ bias,
    float* __restrict__ out, int out_off, int N) {
    constexpr int HC = NHEAD * C;
    constexpr int G = 64 / C;       // lanes per col position (2 or 4)
    constexpr int HP = NHEAD / G;   // heads per lane (4 or 2)
    const int wave = (blockIdx.x * blockDim.x + threadIdx.x) >> 6;
    if (wave >= N) return;
    const int lane = threadIdx.x & 63;
    const int n = wave;
    const int iA = lane >> 3, hA = lane & 7;    // phase-A role
    const int c = lane & (C - 1);               // phase-B role
    const int hh = lane / C;
    const int row0 = rowptr[n];
    const int deg = rowptr[n + 1] - row0;

    const float adhA = a_d[(size_t)n * NHEAD + hA];
    float adhB[HP];
#pragma unroll
    for (int hp = 0; hp < HP; ++hp) adhB[hp] = a_d[(size_t)n * NHEAD + hp * G + hh];

    float sacc = 0.f;
    float acc[HP];
#pragma unroll
    for (int hp = 0; hp < HP; ++hp) acc[hp] = 0.f;

    for (int base = 0; base < deg; base += 8) {
        const int idx = base + iA;
        int src = 0;
        float ex = 0.f;
        if (idx < deg) {
            src = csr_src[row0 + idx];
            ex = expf(lrelu(a_s[(size_t)src * NHEAD + hA] + adhA));
        }
        sacc += ex;
        const int cnt = min(deg - base, 8);
        for (int e2 = 0; e2 < cnt; ++e2) {
            const int s2 = __shfl(src, e2 * 8, 64);
#pragma unroll
            for (int hp = 0; hp < HP; ++hp) {
                const float exh = __shfl(ex, e2 * 8 + hp * G + hh, 64);
                acc[hp] += exh * xp[(size_t)s2 * HC + (hp * G + hh) * C + c];
            }
        }
    }
    sacc += __shfl_xor(sacc, 8, 64);
    sacc += __shfl_xor(sacc, 16, 64);
    sacc += __shfl_xor(sacc, 32, 64);

    float total = 0.f;
#pragma unroll
    for (int hp = 0; hp < HP; ++hp) {
        const int h = hp * G + hh;
        const float exs = expf(lrelu(a_s[(size_t)n * NHEAD + h] + adhB[hp]));
        const float s_h = __shfl(sacc, h, 64) + exs;
        const float acch = acc[hp] + exs * xp[(size_t)n * HC + h * C + c];
        total += acch / s_h;
    }
#pragma unroll
    for (int off = 32; off >= C; off >>= 1) total += __shfl_xor(total, off, 64);
    if (lane < C) {
        out[(size_t)n * OUT_COLS + out_off + lane] =
            fmaxf(total * (1.f / NHEAD) + bias[lane], 0.f);
    }
}

static inline size_t align_up(size_t x) { return (x + 255) & ~size_t(255); }

extern "C" void kernel_launch(void* const* d_in, const int* in_sizes, int n_in,
                              void* d_out, int out_size, void* d_ws, size_t ws_size,
                              hipStream_t stream) {
    const float* x  = (const float*)d_in[0];
    const int*   ei = (const int*)d_in[1];
    const float* W1  = (const float*)d_in[2];
    const float* as1 = (const float*)d_in[3];
    const float* ad1 = (const float*)d_in[4];
    const float* b1  = (const float*)d_in[5];
    const float* W2  = (const float*)d_in[6];
    const float* as2 = (const float*)d_in[7];
    const float* ad2 = (const float*)d_in[8];
    const float* b2  = (const float*)d_in[9];
    const float* W3  = (const float*)d_in[10];
    const float* as3 = (const float*)d_in[11];
    const float* ad3 = (const float*)d_in[12];
    const float* b3  = (const float*)d_in[13];
    float* out = (float*)d_out;

    const int N = in_sizes[0] / 128;
    const int E = in_sizes[1] / 2;

    // workspace layout (~58 MB)
    char* w = (char*)d_ws;
    float* xp     = (float*)w; w += align_up((size_t)N * 256 * 4);
    float* a_s    = (float*)w; w += align_up((size_t)N * NHEAD * 4);
    float* a_d    = (float*)w; w += align_up((size_t)N * NHEAD * 4);
    int*   deg    = (int*)w;   w += align_up((size_t)N * 4);
    int*   rowptr = (int*)w;   w += align_up((size_t)(N + 1) * 4);
    int*   cursor = (int*)w;   w += align_up((size_t)N * 4);
    int*   csrsrc = (int*)w;   w += align_up((size_t)E * 4);
    int*   bsum   = (int*)w;   w += align_up(((size_t)N / 1024 + 2) * 4);

    const int EB = 256;
    const int eg = (E + EB - 1) / EB;
    const int ntiles = (N + 63) / 64;
    const int ngrid = (N + 3) / 4;          // 4 dst-waves per 256-thread block
    const int NB = (N + 1023) / 1024;       // scan chunks

    // ---- CSR build (once, reused by all 3 layers) ----
    hipMemsetAsync(deg, 0, (size_t)N * 4, stream);
    hist_kernel<<<eg, EB, 0, stream>>>(ei, E, deg);
    blocksum_kernel<<<NB, 256, 0, stream>>>(deg, N, bsum);
    bscan_kernel<<<1, 64, 0, stream>>>(bsum, NB);
    rowptr_kernel<<<NB, 256, 0, stream>>>(deg, bsum, N, E, rowptr, cursor);
    scatter_kernel<<<eg, EB, 0, stream>>>(ei, E, cursor, csrsrc);

    // ---------------- Layer 1: din=128, C=32, HC=256 ----------------
    proj_kernel<128, 256, 32><<<dim3(2, ntiles), 256, 0, stream>>>(
        x, 128, 0, W1, as1, ad1, xp, a_s, a_d, N);
    aggr_kernel<32><<<ngrid, 256, 0, stream>>>(rowptr, csrsrc, a_s, a_d, xp, b1, out, 0, N);

    // ---------------- Layer 2: din=32, C=16, HC=128 (input = out[:,0:32]) ----------------
    proj_kernel<32, 128, 16><<<dim3(1, ntiles), 256, 0, stream>>>(
        out, OUT_COLS, 0, W2, as2, ad2, xp, a_s, a_d, N);
    aggr_kernel<16><<<ngrid, 256, 0, stream>>>(rowptr, csrsrc, a_s, a_d, xp, b2, out, 32, N);

    // ---------------- Layer 3: din=16, C=32, HC=256 (input = out[:,32:48]) ----------------
    proj_kernel<16, 256, 32><<<dim3(2, ntiles), 256, 0, stream>>>(
        out, OUT_COLS, 32, W3, as3, ad3, xp, a_s, a_d, N);
    aggr_kernel<32><<<ngrid, 256, 0, stream>>>(rowptr, csrsrc, a_s, a_d, xp, b3, out, 48, N);
}

// Round 6
// 266.853 us; speedup vs baseline: 5.7340x; 1.2975x over previous
//
#include <hip/hip_runtime.h>
#include <hip/hip_fp16.h>
#include <math.h>

#define NHEAD 8
#define NEG_SLOPE 0.2f
#define OUT_COLS 80

__device__ __forceinline__ float lrelu(float x) {
    return x > 0.f ? x : NEG_SLOPE * x;
}

// ---------------- projection: outer-product tile, 2 nodes per lane ----------------
// Block = 4 waves. Wave: 128 nodes (lane -> n, n+64) x 32 cols. xp stored fp16 [n][h*C+c].
template<int HC, int C>
__device__ __forceinline__ void proj_epilogue(
    const float (&acc)[32], int n, int n_nodes, int j0, int j0u,
    const float* __restrict__ as_flat, const float* __restrict__ ad_flat,
    __half* __restrict__ xp, float* __restrict__ a_s, float* __restrict__ a_d) {
    float ps[2] = {0.f, 0.f}, pd[2] = {0.f, 0.f};
#pragma unroll
    for (int q = 0; q < 32; ++q) {
        const int g = (C == 16 && q >= 16) ? 1 : 0;
        ps[g] += acc[q] * as_flat[j0u + q];
        pd[g] += acc[q] * ad_flat[j0u + q];
    }
    if (n < n_nodes) {
        __half2 buf[16];
#pragma unroll
        for (int q = 0; q < 16; ++q)
            buf[q] = __float22half2_rn(make_float2(acc[2 * q], acc[2 * q + 1]));
        float4* dst = (float4*)(xp + (size_t)n * HC + j0);
        const float4* srcb = (const float4*)buf;
#pragma unroll
        for (int q = 0; q < 4; ++q) dst[q] = srcb[q];
        if (C == 32) {
            const int h = j0 / 32;
            a_s[(size_t)n * NHEAD + h] = ps[0];
            a_d[(size_t)n * NHEAD + h] = pd[0];
        } else {
            const int h = j0 / 16;
            a_s[(size_t)n * NHEAD + h] = ps[0];
            a_s[(size_t)n * NHEAD + h + 1] = ps[1];
            a_d[(size_t)n * NHEAD + h] = pd[0];
            a_d[(size_t)n * NHEAD + h + 1] = pd[1];
        }
    }
}

template<int DIN, int HC, int C>
__global__ __launch_bounds__(256) void proj_kernel(
    const float* __restrict__ xin, int xstride, int xoff,
    const float* __restrict__ W,
    const float* __restrict__ as_flat, const float* __restrict__ ad_flat,
    __half* __restrict__ xp, float* __restrict__ a_s, float* __restrict__ a_d,
    int n_nodes) {
    const int lane = threadIdx.x & 63;
    const int wv = threadIdx.x >> 6;
    const int j0 = blockIdx.x * 128 + wv * 32;
    const int j0u = __builtin_amdgcn_readfirstlane(j0);
    const int n0 = blockIdx.y * 128 + lane;
    const int nlast = n_nodes - 1;
    const int nc0 = min(n0, nlast);
    const int nc1 = min(n0 + 64, nlast);

    float acc0[32], acc1[32];
#pragma unroll
    for (int q = 0; q < 32; ++q) { acc0[q] = 0.f; acc1[q] = 0.f; }

    const float* __restrict__ xr0 = xin + (size_t)nc0 * xstride + xoff;
    const float* __restrict__ xr1 = xin + (size_t)nc1 * xstride + xoff;

#pragma unroll 2
    for (int k4 = 0; k4 < DIN / 4; ++k4) {
        const float4 xv0 = *(const float4*)(xr0 + k4 * 4);
        const float4 xv1 = *(const float4*)(xr1 + k4 * 4);
#pragma unroll
        for (int kk = 0; kk < 4; ++kk) {
            const float xk0 = kk == 0 ? xv0.x : kk == 1 ? xv0.y : kk == 2 ? xv0.z : xv0.w;
            const float xk1 = kk == 0 ? xv1.x : kk == 1 ? xv1.y : kk == 2 ? xv1.z : xv1.w;
            const float4* __restrict__ W4 =
                (const float4*)(W + (size_t)(k4 * 4 + kk) * HC + j0u);
#pragma unroll
            for (int q = 0; q < 8; ++q) {
                const float4 wq = W4[q];
                acc0[q * 4 + 0] += xk0 * wq.x;  acc1[q * 4 + 0] += xk1 * wq.x;
                acc0[q * 4 + 1] += xk0 * wq.y;  acc1[q * 4 + 1] += xk1 * wq.y;
                acc0[q * 4 + 2] += xk0 * wq.z;  acc1[q * 4 + 2] += xk1 * wq.z;
                acc0[q * 4 + 3] += xk0 * wq.w;  acc1[q * 4 + 3] += xk1 * wq.w;
            }
        }
    }
    proj_epilogue<HC, C>(acc0, n0, n_nodes, j0, j0u, as_flat, ad_flat, xp, a_s, a_d);
    proj_epilogue<HC, C>(acc1, n0 + 64, n_nodes, j0, j0u, as_flat, ad_flat, xp, a_s, a_d);
}

// ---------------- CSR build ----------------
__global__ void hist_kernel(const int* __restrict__ ei, int E, int* __restrict__ deg) {
    const int e = blockIdx.x * blockDim.x + threadIdx.x;
    if (e < E) atomicAdd(&deg[ei[E + e]], 1);
}

__global__ __launch_bounds__(256) void blocksum_kernel(const int* __restrict__ deg, int N,
                                                       int* __restrict__ bsum) {
    __shared__ int red[256];
    const int t = threadIdx.x;
    const int base = blockIdx.x * 1024 + t * 4;
    int s = 0;
    if (base + 3 < N) {
        const int4 v = *(const int4*)(deg + base);
        s = v.x + v.y + v.z + v.w;
    } else {
#pragma unroll
        for (int i = 0; i < 4; ++i) if (base + i < N) s += deg[base + i];
    }
    red[t] = s;
    __syncthreads();
    for (int off = 128; off > 0; off >>= 1) {
        if (t < off) red[t] += red[t + off];
        __syncthreads();
    }
    if (t == 0) bsum[blockIdx.x] = red[0];
}

__global__ __launch_bounds__(64) void bscan_kernel(int* __restrict__ bsum, int NB) {
    const int lane = threadIdx.x;
    int run = 0;
    for (int base = 0; base < NB; base += 64) {
        const int i = base + lane;
        const int v = (i < NB) ? bsum[i] : 0;
        int inc = v;
#pragma unroll
        for (int off = 1; off < 64; off <<= 1) {
            const int u = __shfl_up(inc, off, 64);
            if (lane >= off) inc += u;
        }
        if (i < NB) bsum[i] = run + inc - v;
        run += __shfl(inc, 63, 64);
    }
}

__global__ __launch_bounds__(256) void rowptr_kernel(const int* __restrict__ deg,
                                                     const int* __restrict__ bsum,
                                                     int N, int E,
                                                     int* __restrict__ rowptr,
                                                     int* __restrict__ cursor) {
    __shared__ int tsum[256];
    const int t = threadIdx.x;
    const int base = blockIdx.x * 1024 + t * 4;
    int v[4];
    int s = 0;
#pragma unroll
    for (int i = 0; i < 4; ++i) {
        v[i] = (base + i < N) ? deg[base + i] : 0;
        s += v[i];
    }
    tsum[t] = s;
    __syncthreads();
    for (int off = 1; off < 256; off <<= 1) {
        const int u = (t >= off) ? tsum[t - off] : 0;
        __syncthreads();
        tsum[t] += u;
        __syncthreads();
    }
    int run = bsum[blockIdx.x] + tsum[t] - s;
#pragma unroll
    for (int i = 0; i < 4; ++i) {
        if (base + i < N) {
            rowptr[base + i] = run;
            cursor[base + i] = run;
            run += v[i];
        }
    }
    if (blockIdx.x == 0 && t == 0) rowptr[N] = E;
}

__global__ void scatter_kernel(const int* __restrict__ ei, int E,
                               int* __restrict__ cursor, int* __restrict__ csr_src) {
    const int e = blockIdx.x * blockDim.x + threadIdx.x;
    if (e < E) {
        const int pos = atomicAdd(&cursor[ei[E + e]], 1);
        csr_src[pos] = ei[e];
    }
}

// ---------------- fused softmax+aggregation: one wave per dst ----------------
// Items = deg edges + 1 self-loop. Phase A: lane=(slot,head) computes unnormalized ex.
// Phase B: LPE lanes fetch an edge's full fp16 row as 16B/lane; acc[8] fp32 per lane.
template<int C>
__global__ __launch_bounds__(256) void aggr_kernel(
    const int* __restrict__ rowptr, const int* __restrict__ csr_src,
    const float* __restrict__ a_s, const float* __restrict__ a_d,
    const __half* __restrict__ xp, const float* __restrict__ bias,
    float* __restrict__ out, int out_off, int N) {
    constexpr int HC = NHEAD * C;
    constexpr int LPE = HC / 8;     // lanes per edge-row (32 or 16)
    constexpr int EPW = 64 / LPE;   // edges in flight per wave (2 or 4)
    constexpr int CQ = C / 8;       // c-octs per head (4 or 2)
    const int n = (blockIdx.x * blockDim.x + threadIdx.x) >> 6;
    if (n >= N) return;
    const int lane = threadIdx.x & 63;
    const int iA = lane >> 3, hA = lane & 7;        // phase-A role
    const int le = lane & (LPE - 1);                // phase-B role
    const int epar = lane / LPE;
    const int h = le / CQ;
    const int c0 = (le % CQ) * 8;
    const int row0 = rowptr[n];
    const int deg = rowptr[n + 1] - row0;
    const int items = deg + 1;                      // + self-loop

    const float adhA = a_d[(size_t)n * NHEAD + hA];
    float sacc = 0.f;
    float acc[8];
#pragma unroll
    for (int j = 0; j < 8; ++j) acc[j] = 0.f;

    for (int base = 0; base < items; base += 8) {
        const int idx = base + iA;
        int src = n;
        float ex = 0.f;
        if (idx < items) {
            if (idx < deg) src = csr_src[row0 + idx];
            ex = expf(lrelu(a_s[(size_t)src * NHEAD + hA] + adhA));
        }
        sacc += ex;
        const int cnt = min(items - base, 8);
        for (int g = 0; g < cnt; g += EPW) {
            const int it = g + epar;
            const int srcb = __shfl(src, it * 8, 64);
            const float exb = __shfl(ex, it * 8 + h, 64);
            if (it < cnt) {
                const float4 r = *(const float4*)(xp + (size_t)srcb * HC + h * C + c0);
                const __half2* h2 = (const __half2*)&r;
#pragma unroll
                for (int q = 0; q < 4; ++q) {
                    const float2 f = __half22float2(h2[q]);
                    acc[2 * q]     += exb * f.x;
                    acc[2 * q + 1] += exb * f.y;
                }
            }
        }
    }
    // softmax denominators: reduce over slots -> lane L holds s for head L&7
    sacc += __shfl_xor(sacc, 8, 64);
    sacc += __shfl_xor(sacc, 16, 64);
    sacc += __shfl_xor(sacc, 32, 64);
    const float sinv = 1.f / __shfl(sacc, h, 64);

    // combine edge-parallel copies (same (h,c-oct), different edge subsets)
#pragma unroll
    for (int off = LPE; off < 64; off <<= 1) {
#pragma unroll
        for (int j = 0; j < 8; ++j) acc[j] += __shfl_xor(acc[j], off, 64);
    }
#pragma unroll
    for (int j = 0; j < 8; ++j) acc[j] *= sinv;      // per-head normalize
    // head-mean reduce (over h lanes)
#pragma unroll
    for (int off = CQ; off < LPE; off <<= 1) {
#pragma unroll
        for (int j = 0; j < 8; ++j) acc[j] += __shfl_xor(acc[j], off, 64);
    }
    if (lane < CQ) {
        float v[8];
#pragma unroll
        for (int j = 0; j < 8; ++j)
            v[j] = fmaxf(acc[j] * (1.f / NHEAD) + bias[lane * 8 + j], 0.f);
        float* op = out + (size_t)n * OUT_COLS + out_off + lane * 8;
        *(float4*)op = make_float4(v[0], v[1], v[2], v[3]);
        *(float4*)(op + 4) = make_float4(v[4], v[5], v[6], v[7]);
    }
}

static inline size_t align_up(size_t x) { return (x + 255) & ~size_t(255); }

extern "C" void kernel_launch(void* const* d_in, const int* in_sizes, int n_in,
                              void* d_out, int out_size, void* d_ws, size_t ws_size,
                              hipStream_t stream) {
    const float* x  = (const float*)d_in[0];
    const int*   ei = (const int*)d_in[1];
    const float* W1  = (const float*)d_in[2];
    const float* as1 = (const float*)d_in[3];
    const float* ad1 = (const float*)d_in[4];
    const float* b1  = (const float*)d_in[5];
    const float* W2  = (const float*)d_in[6];
    const float* as2 = (const float*)d_in[7];
    const float* ad2 = (const float*)d_in[8];
    const float* b2  = (const float*)d_in[9];
    const float* W3  = (const float*)d_in[10];
    const float* as3 = (const float*)d_in[11];
    const float* ad3 = (const float*)d_in[12];
    const float* b3  = (const float*)d_in[13];
    float* out = (float*)d_out;

    const int N = in_sizes[0] / 128;
    const int E = in_sizes[1] / 2;

    // workspace layout
    char* w = (char*)d_ws;
    __half* xp    = (__half*)w; w += align_up((size_t)N * 256 * 2);
    float* a_s    = (float*)w;  w += align_up((size_t)N * NHEAD * 4);
    float* a_d    = (float*)w;  w += align_up((size_t)N * NHEAD * 4);
    int*   deg    = (int*)w;    w += align_up((size_t)N * 4);
    int*   rowptr = (int*)w;    w += align_up((size_t)(N + 1) * 4);
    int*   cursor = (int*)w;    w += align_up((size_t)N * 4);
    int*   csrsrc = (int*)w;    w += align_up((size_t)E * 4);
    int*   bsum   = (int*)w;    w += align_up(((size_t)N / 1024 + 2) * 4);

    const int EB = 256;
    const int eg = (E + EB - 1) / EB;
    const int ntiles = (N + 127) / 128;     // 128 nodes per block (2 per lane)
    const int ngrid = (N + 3) / 4;          // 4 dst-waves per 256-thread block
    const int NB = (N + 1023) / 1024;       // scan chunks

    // ---- CSR build (once, reused by all 3 layers) ----
    hipMemsetAsync(deg, 0, (size_t)N * 4, stream);
    hist_kernel<<<eg, EB, 0, stream>>>(ei, E, deg);
    blocksum_kernel<<<NB, 256, 0, stream>>>(deg, N, bsum);
    bscan_kernel<<<1, 64, 0, stream>>>(bsum, NB);
    rowptr_kernel<<<NB, 256, 0, stream>>>(deg, bsum, N, E, rowptr, cursor);
    scatter_kernel<<<eg, EB, 0, stream>>>(ei, E, cursor, csrsrc);

    // ---------------- Layer 1: din=128, C=32, HC=256 ----------------
    proj_kernel<128, 256, 32><<<dim3(2, ntiles), 256, 0, stream>>>(
        x, 128, 0, W1, as1, ad1, xp, a_s, a_d, N);
    aggr_kernel<32><<<ngrid, 256, 0, stream>>>(rowptr, csrsrc, a_s, a_d, xp, b1, out, 0, N);

    // ---------------- Layer 2: din=32, C=16, HC=128 (input = out[:,0:32]) ----------------
    proj_kernel<32, 128, 16><<<dim3(1, ntiles), 256, 0, stream>>>(
        out, OUT_COLS, 0, W2, as2, ad2, xp, a_s, a_d, N);
    aggr_kernel<16><<<ngrid, 256, 0, stream>>>(rowptr, csrsrc, a_s, a_d, xp, b2, out, 32, N);

    // ---------------- Layer 3: din=16, C=32, HC=256 (input = out[:,32:48]) ----------------
    proj_kernel<16, 256, 32><<<dim3(2, ntiles), 256, 0, stream>>>(
        out, OUT_COLS, 32, W3, as3, ad3, xp, a_s, a_d, N);
    aggr_kernel<32><<<ngrid, 256, 0, stream>>>(rowptr, csrsrc, a_s, a_d, xp, b3, out, 48, N);
}